// Round 9
// baseline (9691.528 us; speedup 1.0000x reference)
//
#include <hip/hip_runtime.h>

typedef _Float16 half2_t __attribute__((ext_vector_type(2)));
typedef _Float16 half8_t __attribute__((ext_vector_type(8)));
typedef float floatx4 __attribute__((ext_vector_type(4)));
typedef unsigned int u32;

#define BB 64
#define TT 2048
#define II 128
#define HH 256
#define CC 64
#define G3 (3*HH)          // 768
#define MTOT (BB*TT)       // 131072

static __device__ __forceinline__ float dot2f(half2_t a, half2_t b, float c) {
#if __has_builtin(__builtin_amdgcn_fdot2)
    return __builtin_amdgcn_fdot2(a, b, c, false);
#else
    return c + (float)a[0]*(float)b[0] + (float)a[1]*(float)b[1];
#endif
}

static __device__ __forceinline__ half2_t bch2(u32 x) {
    return __builtin_bit_cast(half2_t, x);
}

static __device__ __forceinline__ float fast_rcp(float x) {
    return __builtin_amdgcn_rcpf(x);
}

// DPP quad_perm helpers. 0xB1=[1,0,3,2] (xor1), 0x4E=[2,3,0,1] (xor2).
static __device__ __forceinline__ float pair_sum(float x) {   // lanes t,t^1 both get sum
    int i = __builtin_bit_cast(int, x);
    int a = __builtin_amdgcn_mov_dpp(i, 0xB1, 0xF, 0xF, true);
    return x + __builtin_bit_cast(float, a);
}
static __device__ __forceinline__ float dpp_xor2(float x) {   // value from lane t^2
    int i = __builtin_bit_cast(int, x);
    int a = __builtin_amdgcn_mov_dpp(i, 0x4E, 0xF, 0xF, true);
    return __builtin_bit_cast(float, a);
}

// ---------------------------------------------------------------------------
// MFMA GEMM (256 thr): C[M,N] = A[M,K] @ W[N,K]^T + bias. (round-1 validated)
// Used for GEMM1 (gx0) and GEMM3 (classifier head).
// ---------------------------------------------------------------------------
template<typename AT, typename CT>
__global__ __launch_bounds__(256, 2)
void gemm_mfma(const AT* __restrict__ A, const float* __restrict__ W,
               const float* __restrict__ bias, CT* __restrict__ Cout,
               int M, int N, int K)
{
    __shared__ alignas(16) u32 As32[128 * 32];
    __shared__ alignas(16) u32 Bs32[64 * 32];

    const int tid  = threadIdx.x;
    const int lane = tid & 63;
    const int wave = tid >> 6;
    const int wm   = wave >> 1;
    const int wn   = wave & 1;
    const int m0   = blockIdx.y * 128;
    const int n0   = blockIdx.x * 64;
    const int lr   = lane & 15;
    const int lg   = lane >> 4;

    floatx4 acc[4][2] = {};

    for (int kc = 0; kc < K; kc += 64) {
        #pragma unroll
        for (int it = 0; it < 4; ++it) {
            const int s    = it * 256 + tid;
            const int row  = s >> 3;
            const int slot = s & 7;
            const AT* src  = A + (size_t)(m0 + row) * K + kc + slot * 8;
            half8_t v;
            if constexpr (sizeof(AT) == 2) {
                v = *reinterpret_cast<const half8_t*>(src);
            } else {
                const float4* s4 = reinterpret_cast<const float4*>(src);
                float4 lo = s4[0], hi = s4[1];
                v[0] = (_Float16)lo.x; v[1] = (_Float16)lo.y;
                v[2] = (_Float16)lo.z; v[3] = (_Float16)lo.w;
                v[4] = (_Float16)hi.x; v[5] = (_Float16)hi.y;
                v[6] = (_Float16)hi.z; v[7] = (_Float16)hi.w;
            }
            const int sw = slot ^ (row & 7);
            *reinterpret_cast<half8_t*>(&As32[row * 32 + sw * 4]) = v;
        }
        #pragma unroll
        for (int it = 0; it < 2; ++it) {
            const int s    = it * 256 + tid;
            const int row  = s >> 3;
            const int slot = s & 7;
            const float* src = W + (size_t)(n0 + row) * K + kc + slot * 8;
            const float4* s4 = reinterpret_cast<const float4*>(src);
            float4 lo = s4[0], hi = s4[1];
            half8_t v;
            v[0] = (_Float16)lo.x; v[1] = (_Float16)lo.y;
            v[2] = (_Float16)lo.z; v[3] = (_Float16)lo.w;
            v[4] = (_Float16)hi.x; v[5] = (_Float16)hi.y;
            v[6] = (_Float16)hi.z; v[7] = (_Float16)hi.w;
            const int sw = slot ^ (row & 7);
            *reinterpret_cast<half8_t*>(&Bs32[row * 32 + sw * 4]) = v;
        }
        __syncthreads();

        #pragma unroll
        for (int ks = 0; ks < 2; ++ks) {
            half8_t af[4], bf[2];
            #pragma unroll
            for (int fm = 0; fm < 4; ++fm) {
                const int row  = wm * 64 + fm * 16 + lr;
                const int slot = ks * 4 + lg;
                const int sw   = slot ^ (row & 7);
                af[fm] = *reinterpret_cast<const half8_t*>(&As32[row * 32 + sw * 4]);
            }
            #pragma unroll
            for (int fn = 0; fn < 2; ++fn) {
                const int row  = wn * 32 + fn * 16 + lr;
                const int slot = ks * 4 + lg;
                const int sw   = slot ^ (row & 7);
                bf[fn] = *reinterpret_cast<const half8_t*>(&Bs32[row * 32 + sw * 4]);
            }
            #pragma unroll
            for (int fm = 0; fm < 4; ++fm)
                #pragma unroll
                for (int fn = 0; fn < 2; ++fn)
                    acc[fm][fn] = __builtin_amdgcn_mfma_f32_16x16x32_f16(
                        af[fm], bf[fn], acc[fm][fn], 0, 0, 0);
        }
        __syncthreads();
    }

    #pragma unroll
    for (int fn = 0; fn < 2; ++fn) {
        const int n = n0 + wn * 32 + fn * 16 + lr;
        const float bv = bias[n];
        #pragma unroll
        for (int fm = 0; fm < 4; ++fm) {
            #pragma unroll
            for (int r = 0; r < 4; ++r) {
                const int m = m0 + wm * 64 + fm * 16 + lg * 4 + r;
                Cout[(size_t)m * N + n] = (CT)(acc[fm][fn][r] + bv);
            }
        }
    }
}

// ---------------------------------------------------------------------------
// Scan core (v8 structure, validated): one WG per batch element, 512 threads.
// LAYER 0 (producer): publishes prog[b] = completed steps every 16 steps.
// LAYER 1 (consumer): spins on done[b][tc]==12 before each 128-step chunk of
// gx (written concurrently by the B-role GEMM tiles).
// ---------------------------------------------------------------------------
template<int LAYER>
static __device__ __forceinline__
void scan_core(int b, const _Float16* __restrict__ gx,
               const float* __restrict__ Whh, const float* __restrict__ bhh,
               _Float16* __restrict__ hout, u32* prog, u32* done, u32* HsU)
{
    const int t  = threadIdx.x;
    const int j  = t >> 1;
    const int kh = t & 1;

    half2_t w0[64], w1[64], w2[64];
    {
        const float2* q0 = reinterpret_cast<const float2*>(Whh + (size_t)j * HH + kh * 128);
        const float2* q1 = q0 + 128 * HH;
        const float2* q2 = q0 + 256 * HH;
        #pragma unroll
        for (int i = 0; i < 64; ++i) {
            const float2 a = q0[i], c = q1[i], d = q2[i];
            w0[i] = half2_t{(_Float16)a.x, (_Float16)a.y};
            w1[i] = half2_t{(_Float16)c.x, (_Float16)c.y};
            w2[i] = half2_t{(_Float16)d.x, (_Float16)d.y};
        }
    }
    const float bh_r = bhh[j], bh_z = bhh[HH + j], bh_n = bhh[2*HH + j];

    if (t < 272) HsU[t] = 0u;           // zero both padded h buffers
    float hprev = 0.f;

    const _Float16* gp = gx + (size_t)b * TT * G3 + j;
    u32* opw = (u32*)(hout + (size_t)b * TT * HH);

    if (LAYER == 1) {                   // wait for gx chunk 0 (tc = 0)
        if (t == 0)
            while (__hip_atomic_load(&done[b * 16], __ATOMIC_ACQUIRE,
                                     __HIP_MEMORY_SCOPE_AGENT) < 12u)
                __builtin_amdgcn_s_sleep(16);
        __builtin_amdgcn_s_barrier();
        __threadfence();                // invalidate stale cache before gx reads
    }

    _Float16 pxr = gp[0], pxz = gp[HH], pxn = gp[2*HH];
    __syncthreads();

    for (int step = 0; step < TT; ++step) {
        if (LAYER == 1) {               // gate the upcoming prefetch's chunk
            const int nx = step + 1;
            if ((nx & 127) == 0 && nx < TT) {
                if (t == 0)
                    while (__hip_atomic_load(&done[b * 16 + (nx >> 7)], __ATOMIC_ACQUIRE,
                                             __HIP_MEMORY_SCOPE_AGENT) < 12u)
                        __builtin_amdgcn_s_sleep(16);
                __builtin_amdgcn_s_barrier();
                __threadfence();
            }
        }
        // prefetch NEXT step's gx (full-step slack covers latency)
        const _Float16 nxr = gp[G3];
        const _Float16 nxz = gp[G3 + HH];
        const _Float16 nxn = gp[G3 + 2*HH];

        // 16 x ds_read_b128 over this thread's 128-value k-half (padded layout)
        const uint4* hb = reinterpret_cast<const uint4*>(HsU + (step & 1) * 136 + kh * 68);
        float ar = 0.f, az = 0.f, an = 0.f;
        #pragma unroll
        for (int c = 0; c < 16; ++c) {
            const uint4 hv = hb[c];
            const half2_t ha = bch2(hv.x), hc = bch2(hv.y);
            const half2_t hd = bch2(hv.z), he = bch2(hv.w);
            ar = dot2f(ha, w0[4*c+0], ar); az = dot2f(ha, w1[4*c+0], az); an = dot2f(ha, w2[4*c+0], an);
            ar = dot2f(hc, w0[4*c+1], ar); az = dot2f(hc, w1[4*c+1], az); an = dot2f(hc, w2[4*c+1], an);
            ar = dot2f(hd, w0[4*c+2], ar); az = dot2f(hd, w1[4*c+2], az); an = dot2f(hd, w2[4*c+2], an);
            ar = dot2f(he, w0[4*c+3], ar); az = dot2f(he, w1[4*c+3], az); an = dot2f(he, w2[4*c+3], an);
        }
        ar = pair_sum(ar);
        az = pair_sum(az);
        an = pair_sum(an);

        const float r = fast_rcp(1.f + __expf(-((float)pxr + ar + bh_r)));
        const float z = fast_rcp(1.f + __expf(-((float)pxz + az + bh_z)));
        const float e = __expf(2.f * ((float)pxn + r * (an + bh_n)));
        const float n = 1.f - 2.f * fast_rcp(e + 1.f);
        const float hnew = (1.f - z) * n + z * hprev;
        hprev = hnew;

        const float hoth = dpp_xor2(hnew);     // row j^1's value
        if ((t & 3) == 0) {
            const half2_t hp{(_Float16)hnew, (_Float16)hoth};
            const u32 pu = __builtin_bit_cast(u32, hp);
            const int m = t >> 2;
            HsU[((step + 1) & 1) * 136 + (m >> 6) * 68 + (m & 63)] = pu;
            opw[m] = pu;
        }
        asm volatile("s_waitcnt lgkmcnt(0)" ::: "memory");
        __builtin_amdgcn_s_barrier();

        if (LAYER == 0 && (step & 15) == 15) {
            __threadfence();                   // flush this thread's h0 stores
            __builtin_amdgcn_s_barrier();      // all threads fenced
            if (t == 0)
                __hip_atomic_store(&prog[b], (u32)(step + 1), __ATOMIC_RELEASE,
                                   __HIP_MEMORY_SCOPE_AGENT);
        }

        gp += G3; opw += HH/2;
        pxr = nxr; pxz = nxz; pxn = nxn;
    }
}

// ---------------------------------------------------------------------------
// B-role: one 128(M-rows = 128 timesteps of one batch) x 64(N) x K=256 tile of
// gx1 = h0 @ W_ih1^T + b_ih1, computed with MFMA after A's progress covers it.
// Writes IN PLACE over consumed gx0 rows. 512 threads = 8 waves (4x2).
// ---------------------------------------------------------------------------
static __device__ void gemm_role(int gid, const _Float16* __restrict__ hsrc,
                                 const float* __restrict__ W, const float* __restrict__ bias,
                                 _Float16* __restrict__ gout, u32* prog, u32* done, u32* SH)
{
    const int nt = gid % 12;            // n-tile 0..11
    const int y  = gid / 12;            // tc-major: y = tc*64 + b
    const int tc = y >> 6;              // 0..15
    const int bb = y & 63;
    const int tid = threadIdx.x;

    if (tid == 0) {
        const u32 need = (u32)((tc + 1) * 128);
        while (__hip_atomic_load(&prog[bb], __ATOMIC_ACQUIRE,
                                 __HIP_MEMORY_SCOPE_AGENT) < need)
            __builtin_amdgcn_s_sleep(32);
    }
    __syncthreads();
    __threadfence();                    // invalidate stale h0 lines

    u32* As32 = SH;                     // 128*32 u32 (16 KB)
    u32* Bs32 = SH + 128 * 32;          // 64*32 u32 (8 KB)

    const int lane = tid & 63;
    const int wave = tid >> 6;          // 0..7
    const int wm   = wave >> 1;         // 0..3 -> m offset 32*wm
    const int wn   = wave & 1;          // 0..1 -> n offset 32*wn
    const size_t m0 = (size_t)bb * TT + (size_t)tc * 128;
    const int n0   = nt * 64;
    const int lr   = lane & 15;
    const int lg   = lane >> 4;

    floatx4 acc[2][2] = {};

    for (int kc = 0; kc < HH; kc += 64) {
        #pragma unroll
        for (int it = 0; it < 2; ++it) {
            const int s    = it * 512 + tid;
            const int row  = s >> 3;
            const int slot = s & 7;
            const _Float16* src = hsrc + (m0 + row) * HH + kc + slot * 8;
            const half8_t v = *reinterpret_cast<const half8_t*>(src);
            const int sw = slot ^ (row & 7);
            *reinterpret_cast<half8_t*>(&As32[row * 32 + sw * 4]) = v;
        }
        {
            const int row  = tid >> 3;
            const int slot = tid & 7;
            const float* src = W + (size_t)(n0 + row) * HH + kc + slot * 8;
            const float4 lo = reinterpret_cast<const float4*>(src)[0];
            const float4 hi = reinterpret_cast<const float4*>(src)[1];
            half8_t v;
            v[0] = (_Float16)lo.x; v[1] = (_Float16)lo.y;
            v[2] = (_Float16)lo.z; v[3] = (_Float16)lo.w;
            v[4] = (_Float16)hi.x; v[5] = (_Float16)hi.y;
            v[6] = (_Float16)hi.z; v[7] = (_Float16)hi.w;
            const int sw = slot ^ (row & 7);
            *reinterpret_cast<half8_t*>(&Bs32[row * 32 + sw * 4]) = v;
        }
        __syncthreads();

        #pragma unroll
        for (int ks = 0; ks < 2; ++ks) {
            half8_t af[2], bf[2];
            #pragma unroll
            for (int fm = 0; fm < 2; ++fm) {
                const int row  = wm * 32 + fm * 16 + lr;
                const int slot = ks * 4 + lg;
                const int sw   = slot ^ (row & 7);
                af[fm] = *reinterpret_cast<const half8_t*>(&As32[row * 32 + sw * 4]);
            }
            #pragma unroll
            for (int fn = 0; fn < 2; ++fn) {
                const int row  = wn * 32 + fn * 16 + lr;
                const int slot = ks * 4 + lg;
                const int sw   = slot ^ (row & 7);
                bf[fn] = *reinterpret_cast<const half8_t*>(&Bs32[row * 32 + sw * 4]);
            }
            #pragma unroll
            for (int fm = 0; fm < 2; ++fm)
                #pragma unroll
                for (int fn = 0; fn < 2; ++fn)
                    acc[fm][fn] = __builtin_amdgcn_mfma_f32_16x16x32_f16(
                        af[fm], bf[fn], acc[fm][fn], 0, 0, 0);
        }
        __syncthreads();
    }

    #pragma unroll
    for (int fn = 0; fn < 2; ++fn) {
        const int n = n0 + wn * 32 + fn * 16 + lr;
        const float bv = bias[n];
        #pragma unroll
        for (int fm = 0; fm < 2; ++fm) {
            #pragma unroll
            for (int r = 0; r < 4; ++r) {
                const size_t m = m0 + wm * 32 + fm * 16 + lg * 4 + r;
                gout[m * G3 + n] = (_Float16)(acc[fm][fn][r] + bv);
            }
        }
    }
    __threadfence();                    // flush gx1 stores
    __syncthreads();                    // all threads fenced before the count
    if (tid == 0) atomicAdd(&done[bb * 16 + tc], 1u);
}

// ---------------------------------------------------------------------------
// Fused middle phase: blocks 0..63 = scan layer0 (A), 64..127 = scan layer1
// (C), 128.. = gx1 GEMM tiles (B). A/C dispatch first (in-order), 1 block/CU
// (register-bound) -> 128 CUs scan concurrently, B churns the other 128.
// ---------------------------------------------------------------------------
__global__ __attribute__((amdgpu_flat_work_group_size(512, 512),
                          amdgpu_waves_per_eu(2, 2)))
void fused_mid(_Float16* __restrict__ gxbuf, _Float16* __restrict__ hbuf,
               const float* __restrict__ Whh0, const float* __restrict__ bhh0,
               const float* __restrict__ Wih1, const float* __restrict__ bih1,
               const float* __restrict__ Whh1, const float* __restrict__ bhh1,
               u32* flags)
{
    __shared__ alignas(16) u32 SH[6144];    // 24 KB, shared across roles
    u32* prog = flags;                      // [64]
    u32* done = flags + 64;                 // [64*16]
    const int bid = blockIdx.x;
    if (bid < BB) {
        scan_core<0>(bid, gxbuf, Whh0, bhh0, hbuf, prog, done, SH);
    } else if (bid < 2 * BB) {
        scan_core<1>(bid - BB, gxbuf, Whh1, bhh1, hbuf, prog, done, SH);
    } else {
        gemm_role(bid - 2 * BB, hbuf, Wih1, bih1, gxbuf, prog, done, SH);
    }
}

// ---------------------------------------------------------------------------
extern "C" void kernel_launch(void* const* d_in, const int* in_sizes, int n_in,
                              void* d_out, int out_size, void* d_ws, size_t ws_size,
                              hipStream_t stream) {
    const float* x    = (const float*)d_in[0];
    const float* Wih0 = (const float*)d_in[1];
    const float* Whh0 = (const float*)d_in[2];
    const float* bih0 = (const float*)d_in[3];
    const float* bhh0 = (const float*)d_in[4];
    const float* Wih1 = (const float*)d_in[5];
    const float* Whh1 = (const float*)d_in[6];
    const float* bih1 = (const float*)d_in[7];
    const float* bhh1 = (const float*)d_in[8];
    const float* fcw  = (const float*)d_in[9];
    const float* fcb  = (const float*)d_in[10];
    float* out = (float*)d_out;

    // workspace: gx buffer (192 MiB, holds gx0 then gx1 in place) + h buffer
    // (64 MiB, holds h0 then h1 in place) = 256 MiB total, as before.
    _Float16* gxbuf = (_Float16*)d_ws;
    _Float16* hbuf  = (_Float16*)((char*)d_ws + (size_t)MTOT * G3 * sizeof(_Float16));

    // sync flags live at the start of d_out (overwritten by the final GEMM)
    u32* flags = (u32*)d_out;
    hipMemsetAsync(d_out, 0, (64 + 64 * 16) * sizeof(u32), stream);

    // 1) gx0 = x @ W_ih0^T + b_ih0
    gemm_mfma<float, _Float16><<<dim3(G3/64, MTOT/128), dim3(256), 0, stream>>>(
        x, Wih0, bih0, gxbuf, MTOT, G3, II);
    // 2) fused: scan0 || gx1-GEMM || scan1  (grid: 64 A + 64 C + 12288 B)
    fused_mid<<<dim3(2 * BB + 12 * 1024), dim3(512), 0, stream>>>(
        gxbuf, hbuf, Whh0, bhh0, Wih1, bih1, Whh1, bhh1, flags);
    // 3) out = h1 @ fc_w^T + fc_b
    gemm_mfma<_Float16, float><<<dim3(CC/64, MTOT/128), dim3(256), 0, stream>>>(
        hbuf, fcw, fcb, out, MTOT, CC, HH);
}